// Round 3
// baseline (209.001 us; speedup 1.0000x reference)
//
#include <hip/hip_runtime.h>
#include <hip/hip_cooperative_groups.h>
#include <math.h>

namespace cg = cooperative_groups;

// Fully-fused spectral NS projection step (512x512, fp32, periodic).
//   phase A (block=row i):  partial = -adv + nu*lap + F;  z=p0+i*p1; row FFT;
//                           write Z transposed (Zt[j][i]) so phase B reads coalesced
//   phase B (block=col j):  fwd col FFT of cols j and mj=512-j (redundant mj FFT
//                           resolves the -k cross-column dependency), spectral
//                           multiplier for the exact 1000-step Jacobi operator,
//                           inverse col FFT, write W1[i][j] (strided)
//   phase C (block=row i):  inverse row FFT, out = p - (gx, gy)
// Multiplier (exact identity, diagonal in Fourier space):
//   M = r^1000 - (1-r^1000)/(4-s),  r=s/4,  s=2cos ai+2cos aj
//   4-s = 4sin^2(ai/2)+4sin^2(aj/2)  (cancellation-free)
//   W(k) = (beta/2)[(sx^2+sy^2) Z(k) + (sx+i sy)^2 conj(Z(-k))], beta=-10 M/512^2

#define HH 512
#define WW 512
#define NCELL (HH * WW)
#define NU_C 0.1f
#define PI_F 3.14159265358979323846f

struct Smem {
    float2 bufA[512];
    float2 bufB[512];
    float2 zm[512];
    float2 tw[256];
};

// 512-pt radix-2 Stockham, 256 threads, LDS ping-pong. sgn=+1 fwd, -1 inv.
__device__ __forceinline__ float2* fft512(float2* a, float2* b,
                                          const float2* tw, int t, float sgn) {
    float2* src = a;
    float2* dst = b;
#pragma unroll
    for (int s = 0; s < 9; ++s) {
        int Ls = 1 << s;
        int pp = t & (Ls - 1);
        int q  = t >> s;
        float2 w = tw[pp << (8 - s)];
        float wy = sgn * w.y;
        float2 xa = src[q * Ls + pp];
        float2 xb = src[q * Ls + pp + 256];
        float wbx = w.x * xb.x - wy * xb.y;
        float wby = w.x * xb.y + wy * xb.x;
        dst[q * 2 * Ls + pp]      = make_float2(xa.x + wbx, xa.y + wby);
        dst[q * 2 * Ls + pp + Ls] = make_float2(xa.x - wbx, xa.y - wby);
        float2* tmp = src; src = dst; dst = tmp;
        __syncthreads();
    }
    return src;   // = bufB after 9 stages
}

__device__ __forceinline__ void build_tw(Smem& sm, int t) {
    float ang = -PI_F * (float)t * (1.0f / 256.0f);
    float sn, cs;
    sincosf(ang, &sn, &cs);
    sm.tw[t] = make_float2(cs, sn);
}

__device__ void phaseA(Smem& sm, int i, int t,
                       const float* __restrict__ X, const float* __restrict__ F,
                       float* __restrict__ p, float2* __restrict__ Zt) {
    build_tw(sm, t);
    int ip = (i + 1) & 511, im = (i + 511) & 511;
    const float* X0 = X;
    const float* X1 = X + NCELL;
#pragma unroll
    for (int e = 0; e < 2; ++e) {
        int j = t + e * 256;
        int jp = (j + 1) & 511, jm = (j + 511) & 511;
        float x0c = X0[i * WW + j], x1c = X1[i * WW + j];
        float aip = X0[ip * WW + j], aim = X0[im * WW + j];
        float ajp = X0[i * WW + jp], ajm = X0[i * WW + jm];
        float p0 = -(x0c * (aip - aim) * 0.5f + x1c * (ajp - ajm) * 0.5f)
                 + NU_C * (aip + aim + ajp + ajm - 4.0f * x0c) + F[i * WW + j];
        float bip = X1[ip * WW + j], bim = X1[im * WW + j];
        float bjp = X1[i * WW + jp], bjm = X1[i * WW + jm];
        float p1 = -(x0c * (bip - bim) * 0.5f + x1c * (bjp - bjm) * 0.5f)
                 + NU_C * (bip + bim + bjp + bjm - 4.0f * x1c) + F[NCELL + i * WW + j];
        p[i * WW + j] = p0;
        p[NCELL + i * WW + j] = p1;
        sm.bufA[j] = make_float2(p0, p1);
    }
    __syncthreads();
    float2* res = fft512(sm.bufA, sm.bufB, sm.tw, t, 1.0f);
    Zt[t * 512 + i]         = res[t];
    Zt[(t + 256) * 512 + i] = res[t + 256];
}

__device__ void phaseB(Smem& sm, int j, int t,
                       const float2* __restrict__ Zt, float2* __restrict__ W1) {
    build_tw(sm, t);
    int mj = (WW - j) & 511;
    // forward FFT of column mj -> zm
    sm.bufA[t]       = Zt[mj * 512 + t];
    sm.bufA[t + 256] = Zt[mj * 512 + t + 256];
    __syncthreads();
    float2* res = fft512(sm.bufA, sm.bufB, sm.tw, t, 1.0f);
    sm.zm[t]       = res[t];
    sm.zm[t + 256] = res[t + 256];
    __syncthreads();
    // forward FFT of column j
    sm.bufA[t]       = Zt[j * 512 + t];
    sm.bufA[t + 256] = Zt[j * 512 + t + 256];
    __syncthreads();
    res = fft512(sm.bufA, sm.bufB, sm.tw, t, 1.0f);

    float shy, chy;
    sincosf(PI_F * (float)j * (1.0f / 512.0f), &shy, &chy);
    float sy = 2.0f * shy * chy;   // sin(2*pi*j/512)
    float qy = shy * shy;          // sin^2(pi*j/512)
    float Wx[2], Wy[2];
#pragma unroll
    for (int e = 0; e < 2; ++e) {
        int ki = t + e * 256;
        int mi = (HH - ki) & 511;
        float shx, chx;
        sincosf(PI_F * (float)ki * (1.0f / 512.0f), &shx, &chx);
        float sx = 2.0f * shx * chx;
        float qx = shx * shx;
        float qs = qx + qy;        // (4-s)/4, in [0,2]; 0 only at k=0
        float beta = 0.0f;
        if (ki != 0 || j != 0) {
            float rN;              // r^1000 = |r|^1000, r = 1-qs
            if (qs < 1.0f)      rN = expf(1000.0f * log1pf(-qs));
            else if (qs > 1.0f) rN = expf(1000.0f * logf(qs - 1.0f));
            else                rN = 0.0f;
            float M = rN - (1.0f - rN) / (4.0f * qs);
            beta = -10.0f * M * (1.0f / (512.0f * 512.0f));
        }
        float su  = sx * sx + sy * sy;
        float u2x = sx * sx - sy * sy;
        float u2y = 2.0f * sx * sy;
        float2 z  = res[ki];
        float2 zc = sm.zm[mi];
        float cx = zc.x, cy = -zc.y;       // conj
        float tx = u2x * cx - u2y * cy;
        float ty = u2x * cy + u2y * cx;
        float bh = 0.5f * beta;
        Wx[e] = bh * (su * z.x + tx);
        Wy[e] = bh * (su * z.y + ty);
    }
    // own-slot writes; barrier below orders all multiplier reads before FFT
    // stage-0 overwrites bufB
    sm.bufA[t]       = make_float2(Wx[0], Wy[0]);
    sm.bufA[t + 256] = make_float2(Wx[1], Wy[1]);
    __syncthreads();
    res = fft512(sm.bufA, sm.bufB, sm.tw, t, -1.0f);
    W1[t * 512 + j]         = res[t];
    W1[(t + 256) * 512 + j] = res[t + 256];
}

__device__ void phaseC(Smem& sm, int i, int t,
                       const float2* __restrict__ W1, const float* __restrict__ p,
                       float* __restrict__ out) {
    build_tw(sm, t);
    sm.bufA[t]       = W1[i * 512 + t];
    sm.bufA[t + 256] = W1[i * 512 + t + 256];
    __syncthreads();
    float2* res = fft512(sm.bufA, sm.bufB, sm.tw, t, -1.0f);
#pragma unroll
    for (int e = 0; e < 2; ++e) {
        int j = t + e * 256;
        float2 w = res[j];
        out[i * WW + j]         = p[i * WW + j]         - w.x;
        out[NCELL + i * WW + j] = p[NCELL + i * WW + j] - w.y;
    }
}

__global__ __launch_bounds__(256, 2) void fused_all(const float* __restrict__ X,
                                                    const float* __restrict__ F,
                                                    float* __restrict__ out,
                                                    float* __restrict__ ws) {
    __shared__ Smem sm;
    cg::grid_group grid = cg::this_grid();
    int b = blockIdx.x, t = threadIdx.x;
    float*  p  = ws;
    float2* Zt = (float2*)(ws + 2 * NCELL);
    float2* W1 = Zt + NCELL;
    phaseA(sm, b, t, X, F, p, Zt);
    grid.sync();
    phaseB(sm, b, t, Zt, W1);
    grid.sync();
    phaseC(sm, b, t, W1, p, out);
}

// Non-cooperative fallback path (3 dispatches) in case cooperative launch
// fails under graph capture.
__global__ __launch_bounds__(256, 2) void kA(const float* __restrict__ X,
                                             const float* __restrict__ F,
                                             float* __restrict__ p,
                                             float2* __restrict__ Zt) {
    __shared__ Smem sm;
    phaseA(sm, blockIdx.x, threadIdx.x, X, F, p, Zt);
}
__global__ __launch_bounds__(256, 2) void kB(const float2* __restrict__ Zt,
                                             float2* __restrict__ W1) {
    __shared__ Smem sm;
    phaseB(sm, blockIdx.x, threadIdx.x, Zt, W1);
}
__global__ __launch_bounds__(256, 2) void kC(const float2* __restrict__ W1,
                                             const float* __restrict__ p,
                                             float* __restrict__ out) {
    __shared__ Smem sm;
    phaseC(sm, blockIdx.x, threadIdx.x, W1, p, out);
}

extern "C" void kernel_launch(void* const* d_in, const int* in_sizes, int n_in,
                              void* d_out, int out_size, void* d_ws, size_t ws_size,
                              hipStream_t stream) {
    const float* X = (const float*)d_in[1];
    const float* F = (const float*)d_in[2];
    float* out = (float*)d_out;
    float* ws  = (float*)d_ws;

    void* args[] = { (void*)&X, (void*)&F, (void*)&out, (void*)&ws };
    hipError_t err = hipLaunchCooperativeKernel((const void*)fused_all,
                                                dim3(512), dim3(256),
                                                args, 0, stream);
    if (err != hipSuccess) {
        (void)hipGetLastError();   // clear sticky error
        float*  p  = ws;
        float2* Zt = (float2*)(ws + 2 * NCELL);
        float2* W1 = Zt + NCELL;
        kA<<<dim3(512), dim3(256), 0, stream>>>(X, F, p, Zt);
        kB<<<dim3(512), dim3(256), 0, stream>>>(Zt, W1);
        kC<<<dim3(512), dim3(256), 0, stream>>>(W1, p, out);
    }
}

// Round 4
// 79.289 us; speedup vs baseline: 2.6359x; 2.6359x over previous
//
#include <hip/hip_runtime.h>
#include <math.h>

// Spectral NS projection step, 512x512 fp32 periodic — radix-8 register FFT.
//
// 3 kernels, one wave (64 lanes) per 512-pt FFT line, 8 complex elems/lane:
//  A: partial (stencil) + fwd row FFT,  write Z transposed  (Zt[f*512+i])
//  B: fwd col FFT of cols j & 512-j, exact-1000-step-Jacobi spectral
//     multiplier, inv col FFT, write W1[i*512+j]
//  C: inv row FFT + out = partial - grad(phi)
//
// Multiplier (exact identity): M = r^1000 - (1-r^1000)/(4-s), r=s/4,
//   s=2cos ai+2cos aj;  4-s = 4(sin^2(ai/2)+sin^2(aj/2)) (cancellation-free)
//   W(k) = (beta/2)[(sx^2+sy^2) Z(k) + (sx+i sy)^2 conj(Z(-k))], beta=-10M/512^2
//
// Stockham radix-8, 3 stages, reads always buf[t+64m] (conflict-free);
// scatter writes padded by idx+(idx>>3) -> near-uniform bank usage.

#define HH 512
#define WW 512
#define NCELL (HH * WW)
#define NU_C 0.1f
#define PI_F 3.14159265358979323846f
#define PADDED 576   // pad(511)=574

__device__ __forceinline__ int padi(int i) { return i + (i >> 3); }

__device__ __forceinline__ float2 cadd(float2 a, float2 b) { return make_float2(a.x + b.x, a.y + b.y); }
__device__ __forceinline__ float2 csub(float2 a, float2 b) { return make_float2(a.x - b.x, a.y - b.y); }
__device__ __forceinline__ float2 cmul(float2 a, float2 b) {
    return make_float2(a.x * b.x - a.y * b.y, a.x * b.y + a.y * b.x);
}

// twiddle tables are stored FORWARD (cis(-theta)); inverse conjugates on use
template <int S>
__device__ __forceinline__ float2 cmul_tw(float2 a, float2 w) {
    float wy = (S < 0) ? w.y : -w.y;
    return make_float2(a.x * w.x - a.y * wy, a.x * wy + a.y * w.x);
}

// 8-point DFT, S=-1 forward (e^{-2pi i km/8}), S=+1 inverse
template <int S>
__device__ __forceinline__ void bfly8(float2 r[8]) {
    const float c = 0.70710678118654752f;
    const float s = (float)S;
    float2 e0 = cadd(r[0], r[4]), f0 = csub(r[0], r[4]);
    float2 e1 = cadd(r[2], r[6]), f1 = csub(r[2], r[6]);
    float2 g0 = cadd(r[1], r[5]), h0 = csub(r[1], r[5]);
    float2 g1 = cadd(r[3], r[7]), h1 = csub(r[3], r[7]);
    float2 E0 = cadd(e0, e1), E2 = csub(e0, e1);
    float2 if1 = make_float2(-s * f1.y, s * f1.x);       // s*i*f1
    float2 E1 = cadd(f0, if1), E3 = csub(f0, if1);
    float2 O0 = cadd(g0, g1), O2 = csub(g0, g1);
    float2 ih1 = make_float2(-s * h1.y, s * h1.x);
    float2 O1 = cadd(h0, ih1), O3 = csub(h0, ih1);
    float2 t1 = make_float2(c * (O1.x - s * O1.y), c * (O1.y + s * O1.x)); // W8^s1 * O1
    float2 t2 = make_float2(-s * O2.y, s * O2.x);                          // s*i*O2
    float2 t3 = make_float2(-c * (O3.x + s * O3.y), -c * (O3.y - s * O3.x));
    r[0] = cadd(E0, O0); r[4] = csub(E0, O0);
    r[1] = cadd(E1, t1); r[5] = csub(E1, t1);
    r[2] = cadd(E2, t2); r[6] = csub(E2, t2);
    r[3] = cadd(E3, t3); r[7] = csub(E3, t3);
}

struct Twid { float2 s1[8]; float2 s2[8]; };

__device__ __forceinline__ void make_tw(Twid& tw, int t) {
    float sn, cs;
    sincosf(-2.0f * PI_F * (float)(t & 7) * (1.0f / 64.0f), &sn, &cs);
    float2 T1 = make_float2(cs, sn);
    tw.s1[0] = make_float2(1.0f, 0.0f);
#pragma unroll
    for (int m = 1; m < 8; ++m) tw.s1[m] = cmul(tw.s1[m - 1], T1);
    sincosf(-2.0f * PI_F * (float)t * (1.0f / 512.0f), &sn, &cs);
    float2 T2 = make_float2(cs, sn);
    tw.s2[0] = make_float2(1.0f, 0.0f);
#pragma unroll
    for (int m = 1; m < 8; ++m) tw.s2[m] = cmul(tw.s2[m - 1], T2);
}

// 512-pt Stockham radix-8, one wave. In: r[m] = x[t+64m]. Out: r[k] = X[t+64k].
template <int S>
__device__ __forceinline__ void fft512(float2 r[8], const Twid& tw,
                                       float2* b0, float2* b1, int t) {
    bfly8<S>(r);
#pragma unroll
    for (int k = 0; k < 8; ++k) b0[padi(8 * t + k)] = r[k];
    __syncthreads();
#pragma unroll
    for (int m = 0; m < 8; ++m) r[m] = b0[padi(t + 64 * m)];
#pragma unroll
    for (int m = 1; m < 8; ++m) r[m] = cmul_tw<S>(r[m], tw.s1[m]);
    bfly8<S>(r);
    int base = ((t >> 3) << 6) + (t & 7);
#pragma unroll
    for (int k = 0; k < 8; ++k) b1[padi(base + 8 * k)] = r[k];
    __syncthreads();
#pragma unroll
    for (int m = 0; m < 8; ++m) r[m] = b1[padi(t + 64 * m)];
#pragma unroll
    for (int m = 1; m < 8; ++m) r[m] = cmul_tw<S>(r[m], tw.s2[m]);
    bfly8<S>(r);
}

// --------------------------------------------- phase A: stencil + row FFT
__global__ __launch_bounds__(64) void kA(const float* __restrict__ X,
                                         const float* __restrict__ F,
                                         float* __restrict__ p,
                                         float2* __restrict__ Zt) {
    __shared__ float2 b0[PADDED], b1[PADDED];
    int i = blockIdx.x, t = threadIdx.x;
    Twid tw; make_tw(tw, t);
    int ip = (i + 1) & 511, im = (i + 511) & 511;
    const float* X0 = X;
    const float* X1 = X + NCELL;
    float2 r[8];
#pragma unroll
    for (int m = 0; m < 8; ++m) {
        int j = t + 64 * m;
        int jp = (j + 1) & 511, jm = (j + 511) & 511;
        float x0c = X0[i * WW + j], x1c = X1[i * WW + j];
        float aip = X0[ip * WW + j], aim = X0[im * WW + j];
        float ajp = X0[i * WW + jp], ajm = X0[i * WW + jm];
        float p0 = -(x0c * (aip - aim) * 0.5f + x1c * (ajp - ajm) * 0.5f)
                 + NU_C * (aip + aim + ajp + ajm - 4.0f * x0c) + F[i * WW + j];
        float bip = X1[ip * WW + j], bim = X1[im * WW + j];
        float bjp = X1[i * WW + jp], bjm = X1[i * WW + jm];
        float p1 = -(x0c * (bip - bim) * 0.5f + x1c * (bjp - bjm) * 0.5f)
                 + NU_C * (bip + bim + bjp + bjm - 4.0f * x1c) + F[NCELL + i * WW + j];
        p[i * WW + j] = p0;
        p[NCELL + i * WW + j] = p1;
        r[m] = make_float2(p0, p1);
    }
    fft512<-1>(r, tw, b0, b1, t);
#pragma unroll
    for (int k = 0; k < 8; ++k) Zt[(t + 64 * k) * 512 + i] = r[k];
}

// ---------------- phase B: col FFTs + spectral multiplier + inverse col FFT
__global__ __launch_bounds__(64) void kB(const float2* __restrict__ Zt,
                                         float2* __restrict__ W1) {
    __shared__ float2 b0[PADDED], b1[PADDED], zbuf[512];
    int j = blockIdx.x, t = threadIdx.x;
    int mj = (WW - j) & 511;
    Twid tw; make_tw(tw, t);
    float2 r[8];

    // forward FFT of column mj -> zbuf (spectrum, natural order)
#pragma unroll
    for (int m = 0; m < 8; ++m) r[m] = Zt[mj * 512 + t + 64 * m];
    fft512<-1>(r, tw, b0, b1, t);
#pragma unroll
    for (int k = 0; k < 8; ++k) zbuf[t + 64 * k] = r[k];
    __syncthreads();

    // forward FFT of column j
#pragma unroll
    for (int m = 0; m < 8; ++m) r[m] = Zt[j * 512 + t + 64 * m];
    fft512<-1>(r, tw, b0, b1, t);

    // spectral multiplier (exact 1000-step Jacobi solve + gradient)
    float shy, chy;
    sincosf(PI_F * (float)j * (1.0f / 512.0f), &shy, &chy);
    float sy = 2.0f * shy * chy;   // sin(2 pi j/512)
    float qy = shy * shy;          // sin^2(pi j/512)
#pragma unroll
    for (int k = 0; k < 8; ++k) {
        int ki = t + 64 * k;
        int mi = (HH - ki) & 511;
        float shx, chx;
        sincosf(PI_F * (float)ki * (1.0f / 512.0f), &shx, &chx);
        float sx = 2.0f * shx * chx;
        float qx = shx * shx;
        float qs = qx + qy;        // (4-s)/4 in [0,2]; 0 only at k=0
        float beta = 0.0f;
        if (ki != 0 || j != 0) {
            float rN;              // r^1000 = |r|^1000, r = 1-qs
            if (qs < 1.0f)      rN = expf(1000.0f * log1pf(-qs));
            else if (qs > 1.0f) rN = expf(1000.0f * logf(qs - 1.0f));
            else                rN = 0.0f;
            float M = rN - (1.0f - rN) / (4.0f * qs);
            beta = -10.0f * M * (1.0f / (512.0f * 512.0f));
        }
        float su  = sx * sx + sy * sy;
        float u2x = sx * sx - sy * sy;
        float u2y = 2.0f * sx * sy;
        float2 z  = r[k];
        float2 zc = zbuf[mi];
        float cx = zc.x, cy = -zc.y;           // conj(Z(-k))
        float tx = u2x * cx - u2y * cy;
        float ty = u2x * cy + u2y * cx;
        float bh = 0.5f * beta;
        r[k] = make_float2(bh * (su * z.x + tx), bh * (su * z.y + ty));
    }
    __syncthreads();

    // inverse col FFT (input already in registers, natural order)
    fft512<1>(r, tw, b0, b1, t);
#pragma unroll
    for (int k = 0; k < 8; ++k) W1[(t + 64 * k) * 512 + j] = r[k];
}

// --------------------------------------- phase C: inverse row FFT + output
__global__ __launch_bounds__(64) void kC(const float2* __restrict__ W1,
                                         const float* __restrict__ p,
                                         float* __restrict__ out) {
    __shared__ float2 b0[PADDED], b1[PADDED];
    int i = blockIdx.x, t = threadIdx.x;
    Twid tw; make_tw(tw, t);
    float2 r[8];
#pragma unroll
    for (int m = 0; m < 8; ++m) r[m] = W1[i * 512 + t + 64 * m];
    fft512<1>(r, tw, b0, b1, t);
#pragma unroll
    for (int k = 0; k < 8; ++k) {
        int j = t + 64 * k;
        float2 w = r[k];
        out[i * WW + j]         = p[i * WW + j]         - w.x;
        out[NCELL + i * WW + j] = p[NCELL + i * WW + j] - w.y;
    }
}

// ---------------------------------------------------------------------------
extern "C" void kernel_launch(void* const* d_in, const int* in_sizes, int n_in,
                              void* d_out, int out_size, void* d_ws, size_t ws_size,
                              hipStream_t stream) {
    const float* X = (const float*)d_in[1];
    const float* F = (const float*)d_in[2];
    float* out = (float*)d_out;
    float* ws  = (float*)d_ws;

    float*  p  = ws;                          // 2*NCELL floats (2 MB)
    float2* Zt = (float2*)(ws + 2 * NCELL);   // NCELL float2 (2 MB)
    float2* W1 = Zt + NCELL;                  // NCELL float2 (2 MB)

    kA<<<dim3(512), dim3(64), 0, stream>>>(X, F, p, Zt);
    kB<<<dim3(512), dim3(64), 0, stream>>>(Zt, W1);
    kC<<<dim3(512), dim3(64), 0, stream>>>(W1, p, out);
}